// Round 12
// baseline (89.762 us; speedup 1.0000x reference)
//
#include <hip/hip_runtime.h>

typedef __attribute__((ext_vector_type(8))) __bf16 bfv8;
typedef __attribute__((ext_vector_type(4))) float f4v;
typedef __attribute__((ext_vector_type(4))) unsigned short us4v;
typedef __attribute__((ext_vector_type(8))) unsigned short us8v;

static __device__ __forceinline__ unsigned short f2bf(float f){
  union { float f; unsigned u; } v; v.f = f;
  unsigned r = v.u + 0x7fffu + ((v.u >> 16) & 1u);
  return (unsigned short)(r >> 16);
}

static __device__ __forceinline__ unsigned cvtpk(float a, float b){
  unsigned r;
  asm("v_cvt_pk_bf16_f32 %0, %1, %2" : "=v"(r) : "v"(a), "v"(b));
  return r;
}

static __device__ __forceinline__ float fexp2(float x){
#if __has_builtin(__builtin_amdgcn_exp2f)
  return __builtin_amdgcn_exp2f(x);
#else
  return __expf(x * 0.69314718056f);
#endif
}

static __device__ __forceinline__ f4v mfma16(bfv8 a, bfv8 b, f4v c){
  return __builtin_amdgcn_mfma_f32_16x16x32_bf16(a, b, c, 0, 0, 0);
}

// async global->LDS: 16B per lane; LDS dst = wave-uniform base + lane*16
static __device__ __forceinline__ void gload16(const void* g, void* l){
  __builtin_amdgcn_global_load_lds((const __attribute__((address_space(1))) unsigned int*)g,
                                   (__attribute__((address_space(3))) unsigned int*)l,
                                   16, 0, 0);
}

// Fragment layout for a [rows][512] bf16 matrix consumed as MFMA operand rows:
//   off = (row>>4)*8192 + (col>>5)*512 + ((col>>3)&3)*128 + (row&15)*8 + (col&7)

// ---------------- K0: merged weight-convert + GroupNorm stats ----------------
__global__ __launch_bounds__(256) void k_prep(const float* __restrict__ qkvw,
                                              const float* __restrict__ projw,
                                              const float* __restrict__ x,
                                              unsigned short* __restrict__ WQF,
                                              unsigned short* __restrict__ WPF,
                                              float2* __restrict__ part){
  int bid = blockIdx.x;
  if (bid < 1024){
    const float* src; unsigned short* dst; int i;
    if (bid < 768){ src = qkvw; dst = WQF; i = bid*256 + threadIdx.x; }
    else          { src = projw; dst = WPF; i = (bid-768)*256 + threadIdx.x; }
    int o = i >> 7, c4 = (i & 127) << 2;
    float4 v = *(const float4*)(src + (size_t)o*512 + c4);
    us4v w; w[0]=f2bf(v.x); w[1]=f2bf(v.y); w[2]=f2bf(v.z); w[3]=f2bf(v.w);
    size_t off = (size_t)(o>>4)*8192 + ((c4>>5)<<9) + (((c4>>3)&3)<<7) + ((o&15)<<3) + (c4&7);
    *(us4v*)(dst + off) = w;
    return;
  }
  int sb = bid - 1024;
  int bg = sb >> 4, ch = sb & 15;
  const float4* base = (const float4*)(x + (size_t)bg*131072 + (size_t)ch*8192);
  float s=0.f, ss=0.f;
  #pragma unroll
  for (int it=0; it<8; ++it){
    float4 v = base[threadIdx.x + it*256];
    s  += v.x+v.y+v.z+v.w;
    ss += v.x*v.x+v.y*v.y+v.z*v.z+v.w*v.w;
  }
  #pragma unroll
  for (int off=1; off<64; off<<=1){ s += __shfl_xor(s,off); ss += __shfl_xor(ss,off); }
  __shared__ float red[8];
  int wid = threadIdx.x >> 6, l = threadIdx.x & 63;
  if (l==0){ red[wid]=s; red[wid+4]=ss; }
  __syncthreads();
  if (threadIdx.x==0)
    part[sb] = make_float2(red[0]+red[1]+red[2]+red[3],
                           red[4]+red[5]+red[6]+red[7]);
}

// ---------------- K2: GroupNorm finalize + transpose -> AF fragment layout ----------------
__global__ __launch_bounds__(256) void k_gnnorm(const float* __restrict__ x,
                                                const float2* __restrict__ part,
                                                const float* __restrict__ gnw,
                                                const float* __restrict__ gnb,
                                                unsigned short* __restrict__ AF){
  int nt = blockIdx.x & 31, ct = (blockIdx.x>>5)&7, b = blockIdx.x>>8;
  __shared__ float2 sms;
  __shared__ unsigned short tile[64][68];
  int tid = threadIdx.x;
  if (tid == 0){
    int bg = b*8 + ct;
    float s=0.f, ss=0.f;
    for (int i=0;i<16;++i){ float2 p = part[bg*16+i]; s+=p.x; ss+=p.y; }
    float mean = s * (1.f/131072.f);
    float var  = ss * (1.f/131072.f) - mean*mean;
    sms = make_float2(mean, rsqrtf(var + 1e-5f));
  }
  __syncthreads();
  float mean = sms.x, rstd = sms.y;
  int c0 = ct*64, n0 = nt*64;
  #pragma unroll
  for (int pass=0; pass<4; ++pass){
    int i = (tid>>4) + pass*16;
    int fc = tid & 15;
    int c = c0 + i;
    float w  = gnw[c]*rstd;
    float bb = gnb[c] - mean*w;
    float4 v = *(const float4*)(x + ((size_t)(b*512+c))*2048 + n0 + fc*4);
    tile[i][fc*4+0] = f2bf(v.x*w+bb);
    tile[i][fc*4+1] = f2bf(v.y*w+bb);
    tile[i][fc*4+2] = f2bf(v.z*w+bb);
    tile[i][fc*4+3] = f2bf(v.w*w+bb);
  }
  __syncthreads();
  #pragma unroll
  for (int pass=0; pass<2; ++pass){
    int r  = (tid>>3) + pass*32;
    int c8 = tid & 7;
    us8v o;
    #pragma unroll
    for (int u=0;u<8;++u) o[u] = tile[c8*8+u][r];
    int n = n0 + r, c = c0 + c8*8;
    size_t off = (size_t)(b*128 + (n>>4))*8192 + ((c>>5)<<9) + (((c>>3)&3)<<7) + ((n&15)<<3);
    *(us8v*)(AF + off) = o;
  }
}

// ---------------- K3: qkv GEMM v2 (32n x 64o per wave) ----------------
__global__ __launch_bounds__(256) void k_qkv(const unsigned short* __restrict__ AF,
                                             const unsigned short* __restrict__ WQF,
                                             const float* __restrict__ qb,
                                             unsigned short* __restrict__ Qh,
                                             unsigned short* __restrict__ KF,
                                             unsigned short* __restrict__ VF){
  int bid = blockIdx.x;
  int ot = bid % 12; int t2 = bid / 12; int nt = t2 & 31; int b = t2 >> 5;
  int tid = threadIdx.x, wid = tid>>6, l = tid&63, lr = l&15, lg = l>>4;
  int wo = wid & 1, wn = wid >> 1;
  int n0 = nt*64 + wn*32, o0 = ot*128 + wo*64;
  f4v acc[2][4];
  #pragma unroll
  for (int a2=0;a2<2;++a2)
    #pragma unroll
    for (int s=0;s<4;++s) acc[a2][s] = (f4v){0.f,0.f,0.f,0.f};
  const unsigned short* arow = AF + (size_t)(b*128 + (n0>>4))*8192 + l*8;
  const unsigned short* brow = WQF + (size_t)(o0>>4)*8192 + l*8;
  #pragma unroll
  for (int kc=0;kc<16;++kc){
    bfv8 a0 = *(const bfv8*)(arow + kc*512);
    bfv8 a1 = *(const bfv8*)(arow + 8192 + kc*512);
    #pragma unroll
    for (int s=0;s<4;++s){
      bfv8 bb = *(const bfv8*)(brow + s*8192 + kc*512);
      acc[0][s] = mfma16(a0, bb, acc[0][s]);
      acc[1][s] = mfma16(a1, bb, acc[1][s]);
    }
  }
  #pragma unroll
  for (int s=0;s<4;++s){
    int o = o0 + s*16 + lr;
    float bias = qb[o];
    int seg = o >> 9, oo = o & 511, h = oo>>6, dd = oo&63;
    size_t hb = (size_t)(b*8+h)*131072;
    #pragma unroll
    for (int a2=0;a2<2;++a2){
      #pragma unroll
      for (int r=0;r<4;++r){
        int n = n0 + a2*16 + lg*4 + r;
        unsigned short val = f2bf(acc[a2][s][r] + bias);
        if (seg==0)
          Qh[hb + (size_t)n*64 + dd] = val;
        else if (seg==1)
          KF[hb + (n>>4)*1024 + (dd>>5)*512 + ((dd>>3)&3)*128 + (n&15)*8 + (dd&7)] = val;
        else
          VF[hb + (n>>5)*2048 + (dd>>4)*512 + ((n>>3)&3)*128 + (dd&15)*8 + (n&7)] = val;
      }
    }
  }
}

// ---------------- K4: flash attention v11: block-cooperative KV staging ----------------
// 256 blocks (1/CU), 128 q-rows per block (wave w: q0+32w, full 2048-j scan).
// Per 64-j tile: all threads stage K(8KB)+V(8KB) via global_load_lds (dbuf),
// counted vmcnt(4) + raw s_barrier (no __syncthreads: it would drain vmcnt).
__global__ __launch_bounds__(256) void k_attn(const unsigned short* __restrict__ Qh,
                                              const unsigned short* __restrict__ KF,
                                              const unsigned short* __restrict__ VF,
                                              const float* __restrict__ rel,
                                              unsigned short* __restrict__ AOF){
  int did = blockIdx.x;
  int bh = (did & 7)*2 + ((did >> 7) & 1);    // XCD-chunked: 2 heads per XCD
  int qt = (did >> 3) & 15;                   // 16 q-tiles of 128 rows
  int tid = threadIdx.x, wid = tid>>6, l = tid&63, lr = l&15, lg = l>>4;
  __shared__ float slut[32];
  __shared__ __align__(16) char kvs[2][16384]; // [buf][ K 8KB | V 8KB ]
  __shared__ __align__(16) char pbufs[4][4096];
  if (tid < 32){
    int bkt = (tid>=1)+(tid>=4)+(tid>=9)+(tid>=16)+(tid>=25);
    slut[tid] = rel[bkt] * 1.44269504f;       // pre-folded log2(e)
  }
  int q0 = qt*128 + wid*32;
  int dq = q0 >> 8, hqA = (q0 >> 4) & 15, hqB = hqA + 1;  // wave-uniform, hqA even
  int swsq[4];
  #pragma unroll
  for (int r=0;r<4;++r){ int sw = lr - (lg*4+r); swsq[r] = sw*sw; }
  const unsigned short* Qb = Qh + (size_t)bh*131072;
  const char* Kb = (const char*)(KF + (size_t)bh*131072);
  const char* Vb = (const char*)(VF + (size_t)bh*131072);
  bfv8 qf0A = *(const bfv8*)(Qb + (size_t)(q0+lr)*64 + lg*8);
  bfv8 qf1A = *(const bfv8*)(Qb + (size_t)(q0+lr)*64 + 32 + lg*8);
  bfv8 qf0B = *(const bfv8*)(Qb + (size_t)(q0+16+lr)*64 + lg*8);
  bfv8 qf1B = *(const bfv8*)(Qb + (size_t)(q0+16+lr)*64 + 32 + lg*8);
  f4v oA[4], oB[4];
  #pragma unroll
  for (int i2=0;i2<4;++i2){ oA[i2] = (f4v){0.f,0.f,0.f,0.f}; oB[i2] = (f4v){0.f,0.f,0.f,0.f}; }
  float lsA = 0.f, lsB = 0.f;
  char* pwA = pbufs[wid];
  char* pwB = pwA + 2048;
  int swz = (lr&7)<<4;
  int wb16 = wid*1024 + (l&63)*16;            // this thread's 16B slot within a 4KB round
  // prologue: stage tile 0 into buf 0 (4 gloads/thread), then full sync (also covers slut)
  {
    char* dst = kvs[0] + wid*1024;
    const char* ks = Kb + wb16;
    const char* vs = Vb + wb16;
    gload16(ks,        dst);
    gload16(ks + 4096, dst + 4096);
    gload16(vs,        dst + 8192);
    gload16(vs + 4096, dst + 12288);
  }
  __syncthreads();
  #pragma unroll 2
  for (int i=0; i<32; ++i){
    char* kv = kvs[i&1];
    if (i < 31){
      char* dst = kvs[(i+1)&1] + wid*1024;
      const char* ks = Kb + (size_t)(i+1)*8192 + wb16;
      const char* vs = Vb + (size_t)(i+1)*8192 + wb16;
      gload16(ks,        dst);
      gload16(ks + 4096, dst + 4096);
      gload16(vs,        dst + 8192);
      gload16(vs + 4096, dst + 12288);
      asm volatile("s_waitcnt vmcnt(4)" ::: "memory");   // tile i's 4 loads complete
    } else {
      asm volatile("s_waitcnt vmcnt(0)" ::: "memory");
    }
    __builtin_amdgcn_s_barrier();             // all waves' tile-i stores visible
    f4v sa[4], sb[4];
    #pragma unroll
    for (int t=0;t<4;++t){ sa[t] = (f4v){0.f,0.f,0.f,0.f}; sb[t] = (f4v){0.f,0.f,0.f,0.f}; }
    #pragma unroll
    for (int t=0;t<4;++t){
      bfv8 k0 = *(const bfv8*)(kv + t*2048 + l*16);
      bfv8 k1 = *(const bfv8*)(kv + t*2048 + 1024 + l*16);
      sa[t] = mfma16(k0, qf0A, sa[t]);        // S^T: A=K rows (j), B=Q rows (q)
      sa[t] = mfma16(k1, qf1A, sa[t]);
      sb[t] = mfma16(k0, qf0B, sb[t]);
      sb[t] = mfma16(k1, qf1B, sb[t]);
    }
    int dj = i>>2; int sd = dq-dj; int sds = sd*sd;
    int hj0 = (i&3)*4;
    // ---- half A softmax (exp2-folded) ----
    #pragma unroll
    for (int t=0;t<4;++t){
      int sh = hqA - (hj0+t); int sdh = sds + sh*sh;
      float p0 = fexp2(fmaf(sa[t][0], 0.180336878f, slut[(sdh+swsq[0])>>4]));
      float p1 = fexp2(fmaf(sa[t][1], 0.180336878f, slut[(sdh+swsq[1])>>4]));
      float p2 = fexp2(fmaf(sa[t][2], 0.180336878f, slut[(sdh+swsq[2])>>4]));
      float p3 = fexp2(fmaf(sa[t][3], 0.180336878f, slut[(sdh+swsq[3])>>4]));
      lsA += (p0+p1)+(p2+p3);
      uint2 w; w.x = cvtpk(p0,p1); w.y = cvtpk(p2,p3);
      *(uint2*)(pwA + lr*128 + ((32*t + 8*lg) ^ swz)) = w;
    }
    // ---- half B softmax ----
    #pragma unroll
    for (int t=0;t<4;++t){
      int sh = hqB - (hj0+t); int sdh = sds + sh*sh;
      float p0 = fexp2(fmaf(sb[t][0], 0.180336878f, slut[(sdh+swsq[0])>>4]));
      float p1 = fexp2(fmaf(sb[t][1], 0.180336878f, slut[(sdh+swsq[1])>>4]));
      float p2 = fexp2(fmaf(sb[t][2], 0.180336878f, slut[(sdh+swsq[2])>>4]));
      float p3 = fexp2(fmaf(sb[t][3], 0.180336878f, slut[(sdh+swsq[3])>>4]));
      lsB += (p0+p1)+(p2+p3);
      uint2 w; w.x = cvtpk(p0,p1); w.y = cvtpk(p2,p3);
      *(uint2*)(pwB + lr*128 + ((32*t + 8*lg) ^ swz)) = w;
    }
    // ---- PV from staged V (LDS) ----
    #pragma unroll
    for (int kt=0;kt<2;++kt){
      bfv8 pfA = *(const bfv8*)(pwA + lr*128 + ((64*kt + 16*lg) ^ swz));
      bfv8 pfB = *(const bfv8*)(pwB + lr*128 + ((64*kt + 16*lg) ^ swz));
      const char* vt = kv + 8192 + kt*4096;
      #pragma unroll
      for (int d2=0;d2<4;++d2){
        bfv8 vf = *(const bfv8*)(vt + d2*1024 + l*16);
        oA[d2] = mfma16(pfA, vf, oA[d2]);
        oB[d2] = mfma16(pfB, vf, oB[d2]);
      }
    }
    __builtin_amdgcn_s_barrier();             // all waves done with buf before overwrite
  }
  lsA += __shfl_xor(lsA, 16); lsA += __shfl_xor(lsA, 32);
  lsB += __shfl_xor(lsB, 16); lsB += __shfl_xor(lsB, 32);
  int b = bh>>3, h = bh&7;
  #pragma unroll
  for (int r=0;r<4;++r){
    float invA = 1.f / __shfl(lsA, lg*4+r);
    float invB = 1.f / __shfl(lsB, lg*4+r);
    #pragma unroll
    for (int d2=0;d2<4;++d2){
      int c = h*64 + d2*16 + lr;
      size_t cpart = ((size_t)(c>>5)<<9) + (((c>>3)&3)<<7) + (c&7);
      int nA = q0 + lg*4 + r;
      int nB = nA + 16;
      AOF[(size_t)(b*128 + (nA>>4))*8192 + cpart + (nA&15)*8] = f2bf(oA[d2][r]*invA);
      AOF[(size_t)(b*128 + (nB>>4))*8192 + cpart + (nB&15)*8] = f2bf(oB[d2][r]*invB);
    }
  }
}

// ---------------- K5: proj GEMM + bias + residual (fragment-ordered operands) ----------------
__global__ __launch_bounds__(256) void k_proj(const unsigned short* __restrict__ AOF,
                                              const unsigned short* __restrict__ WPF,
                                              const float* __restrict__ pb,
                                              const float* __restrict__ x,
                                              float* __restrict__ out){
  int nt = blockIdx.x & 31, ot = (blockIdx.x>>5)&7, b = blockIdx.x>>8;
  int tid = threadIdx.x, wid = tid>>6, l = tid&63, lr = l&15, lg = l>>4;
  int o0 = ot*64 + wid*16, n0 = nt*64;
  f4v acc[4];
  #pragma unroll
  for (int t=0;t<4;++t) acc[t] = (f4v){0.f,0.f,0.f,0.f};
  const unsigned short* arow = WPF + (size_t)(o0>>4)*8192 + l*8;
  const unsigned short* brow = AOF + (size_t)(b*128 + (n0>>4))*8192 + l*8;
  #pragma unroll
  for (int kc=0;kc<16;++kc){
    bfv8 a = *(const bfv8*)(arow + kc*512);
    #pragma unroll
    for (int t=0;t<4;++t){
      bfv8 bb = *(const bfv8*)(brow + t*8192 + kc*512);
      acc[t] = mfma16(a, bb, acc[t]);
    }
  }
  #pragma unroll
  for (int r=0;r<4;++r){
    int o = o0 + lg*4 + r;
    float bias = pb[o];
    #pragma unroll
    for (int t=0;t<4;++t){
      int n = n0 + t*16 + lr;
      size_t idx = ((size_t)(b*512)+o)*2048 + n;
      out[idx] = acc[t][r] + bias + x[idx];
    }
  }
}

extern "C" void kernel_launch(void* const* d_in, const int* in_sizes, int n_in,
                              void* d_out, int out_size, void* d_ws, size_t ws_size,
                              hipStream_t stream){
  const float* x     = (const float*)d_in[0];
  const float* gnw   = (const float*)d_in[1];
  const float* gnb   = (const float*)d_in[2];
  const float* qkvw  = (const float*)d_in[3];
  const float* qkvb  = (const float*)d_in[4];
  const float* projw = (const float*)d_in[5];
  const float* projb = (const float*)d_in[6];
  const float* rel   = (const float*)d_in[7];
  float* out = (float*)d_out;
  char* ws = (char*)d_ws;
  float2* part           = (float2*)ws;                       // 2 KB
  unsigned short* WQF    = (unsigned short*)(ws + 4096);      // 1536x512 bf16, frag order
  unsigned short* WPF    = (unsigned short*)(ws + 1576960);   // 512x512 bf16, frag order
  unsigned short* AF     = (unsigned short*)(ws + 2101248);   // [2][2048][512] frag order
  unsigned short* Qh     = (unsigned short*)(ws + 6295552);   // [2][8][2048][64] row-major
  unsigned short* KF     = (unsigned short*)(ws + 10489856);  // [2][8] K frag order
  unsigned short* VF     = (unsigned short*)(ws + 14684160);  // [2][8] V frag order
  unsigned short* AOF    = (unsigned short*)(ws + 18878464);  // [2][2048][512] frag order

  hipLaunchKernelGGL(k_prep,   dim3(1280), dim3(256), 0, stream, qkvw, projw, x, WQF, WPF, part);
  hipLaunchKernelGGL(k_gnnorm, dim3(512),  dim3(256), 0, stream, x, part, gnw, gnb, AF);
  hipLaunchKernelGGL(k_qkv,    dim3(768),  dim3(256), 0, stream, AF, WQF, qkvb, Qh, KF, VF);
  hipLaunchKernelGGL(k_attn,   dim3(256),  dim3(256), 0, stream, Qh, KF, VF, rel, AOF);
  hipLaunchKernelGGL(k_proj,   dim3(512),  dim3(256), 0, stream, AOF, WPF, projb, x, out);
}

// Round 13
// 69.346 us; speedup vs baseline: 1.2944x; 1.2944x over previous
//
#include <hip/hip_runtime.h>

typedef __attribute__((ext_vector_type(8))) __bf16 bfv8;
typedef __attribute__((ext_vector_type(4))) float f4v;
typedef __attribute__((ext_vector_type(4))) unsigned short us4v;
typedef __attribute__((ext_vector_type(8))) unsigned short us8v;

static __device__ __forceinline__ unsigned short f2bf(float f){
  union { float f; unsigned u; } v; v.f = f;
  unsigned r = v.u + 0x7fffu + ((v.u >> 16) & 1u);
  return (unsigned short)(r >> 16);
}

static __device__ __forceinline__ unsigned cvtpk(float a, float b){
  unsigned r;
  asm("v_cvt_pk_bf16_f32 %0, %1, %2" : "=v"(r) : "v"(a), "v"(b));
  return r;
}

static __device__ __forceinline__ float fexp2(float x){
#if __has_builtin(__builtin_amdgcn_exp2f)
  return __builtin_amdgcn_exp2f(x);
#else
  return __expf(x * 0.69314718056f);
#endif
}

static __device__ __forceinline__ f4v mfma16(bfv8 a, bfv8 b, f4v c){
  return __builtin_amdgcn_mfma_f32_16x16x32_bf16(a, b, c, 0, 0, 0);
}

// Fragment layout for a [rows][512] bf16 matrix consumed as MFMA operand rows:
//   off = (row>>4)*8192 + (col>>5)*512 + ((col>>3)&3)*128 + (row&15)*8 + (col&7)

// ---------------- K0: merged weight-convert + GroupNorm stats ----------------
__global__ __launch_bounds__(256) void k_prep(const float* __restrict__ qkvw,
                                              const float* __restrict__ projw,
                                              const float* __restrict__ x,
                                              unsigned short* __restrict__ WQF,
                                              unsigned short* __restrict__ WPF,
                                              float2* __restrict__ part){
  int bid = blockIdx.x;
  if (bid < 1024){
    const float* src; unsigned short* dst; int i;
    if (bid < 768){ src = qkvw; dst = WQF; i = bid*256 + threadIdx.x; }
    else          { src = projw; dst = WPF; i = (bid-768)*256 + threadIdx.x; }
    int o = i >> 7, c4 = (i & 127) << 2;
    float4 v = *(const float4*)(src + (size_t)o*512 + c4);
    us4v w; w[0]=f2bf(v.x); w[1]=f2bf(v.y); w[2]=f2bf(v.z); w[3]=f2bf(v.w);
    size_t off = (size_t)(o>>4)*8192 + ((c4>>5)<<9) + (((c4>>3)&3)<<7) + ((o&15)<<3) + (c4&7);
    *(us4v*)(dst + off) = w;
    return;
  }
  int sb = bid - 1024;
  int bg = sb >> 4, ch = sb & 15;
  const float4* base = (const float4*)(x + (size_t)bg*131072 + (size_t)ch*8192);
  float s=0.f, ss=0.f;
  #pragma unroll
  for (int it=0; it<8; ++it){
    float4 v = base[threadIdx.x + it*256];
    s  += v.x+v.y+v.z+v.w;
    ss += v.x*v.x+v.y*v.y+v.z*v.z+v.w*v.w;
  }
  #pragma unroll
  for (int off=1; off<64; off<<=1){ s += __shfl_xor(s,off); ss += __shfl_xor(ss,off); }
  __shared__ float red[8];
  int wid = threadIdx.x >> 6, l = threadIdx.x & 63;
  if (l==0){ red[wid]=s; red[wid+4]=ss; }
  __syncthreads();
  if (threadIdx.x==0)
    part[sb] = make_float2(red[0]+red[1]+red[2]+red[3],
                           red[4]+red[5]+red[6]+red[7]);
}

// ---------------- K2: GroupNorm finalize + transpose -> AF fragment layout ----------------
__global__ __launch_bounds__(256) void k_gnnorm(const float* __restrict__ x,
                                                const float2* __restrict__ part,
                                                const float* __restrict__ gnw,
                                                const float* __restrict__ gnb,
                                                unsigned short* __restrict__ AF){
  int nt = blockIdx.x & 31, ct = (blockIdx.x>>5)&7, b = blockIdx.x>>8;
  __shared__ float2 sms;
  __shared__ unsigned short tile[64][68];
  int tid = threadIdx.x;
  if (tid == 0){
    int bg = b*8 + ct;
    float s=0.f, ss=0.f;
    for (int i=0;i<16;++i){ float2 p = part[bg*16+i]; s+=p.x; ss+=p.y; }
    float mean = s * (1.f/131072.f);
    float var  = ss * (1.f/131072.f) - mean*mean;
    sms = make_float2(mean, rsqrtf(var + 1e-5f));
  }
  __syncthreads();
  float mean = sms.x, rstd = sms.y;
  int c0 = ct*64, n0 = nt*64;
  #pragma unroll
  for (int pass=0; pass<4; ++pass){
    int i = (tid>>4) + pass*16;
    int fc = tid & 15;
    int c = c0 + i;
    float w  = gnw[c]*rstd;
    float bb = gnb[c] - mean*w;
    float4 v = *(const float4*)(x + ((size_t)(b*512+c))*2048 + n0 + fc*4);
    tile[i][fc*4+0] = f2bf(v.x*w+bb);
    tile[i][fc*4+1] = f2bf(v.y*w+bb);
    tile[i][fc*4+2] = f2bf(v.z*w+bb);
    tile[i][fc*4+3] = f2bf(v.w*w+bb);
  }
  __syncthreads();
  #pragma unroll
  for (int pass=0; pass<2; ++pass){
    int r  = (tid>>3) + pass*32;
    int c8 = tid & 7;
    us8v o;
    #pragma unroll
    for (int u=0;u<8;++u) o[u] = tile[c8*8+u][r];
    int n = n0 + r, c = c0 + c8*8;
    size_t off = (size_t)(b*128 + (n>>4))*8192 + ((c>>5)<<9) + (((c>>3)&3)<<7) + ((n&15)<<3);
    *(us8v*)(AF + off) = o;
  }
}

// ---------------- K3: qkv GEMM v2 (32n x 64o per wave) ----------------
__global__ __launch_bounds__(256) void k_qkv(const unsigned short* __restrict__ AF,
                                             const unsigned short* __restrict__ WQF,
                                             const float* __restrict__ qb,
                                             unsigned short* __restrict__ Qh,
                                             unsigned short* __restrict__ KF,
                                             unsigned short* __restrict__ VF){
  int bid = blockIdx.x;
  int ot = bid % 12; int t2 = bid / 12; int nt = t2 & 31; int b = t2 >> 5;
  int tid = threadIdx.x, wid = tid>>6, l = tid&63, lr = l&15, lg = l>>4;
  int wo = wid & 1, wn = wid >> 1;
  int n0 = nt*64 + wn*32, o0 = ot*128 + wo*64;
  f4v acc[2][4];
  #pragma unroll
  for (int a2=0;a2<2;++a2)
    #pragma unroll
    for (int s=0;s<4;++s) acc[a2][s] = (f4v){0.f,0.f,0.f,0.f};
  const unsigned short* arow = AF + (size_t)(b*128 + (n0>>4))*8192 + l*8;
  const unsigned short* brow = WQF + (size_t)(o0>>4)*8192 + l*8;
  #pragma unroll
  for (int kc=0;kc<16;++kc){
    bfv8 a0 = *(const bfv8*)(arow + kc*512);
    bfv8 a1 = *(const bfv8*)(arow + 8192 + kc*512);
    #pragma unroll
    for (int s=0;s<4;++s){
      bfv8 bb = *(const bfv8*)(brow + s*8192 + kc*512);
      acc[0][s] = mfma16(a0, bb, acc[0][s]);
      acc[1][s] = mfma16(a1, bb, acc[1][s]);
    }
  }
  #pragma unroll
  for (int s=0;s<4;++s){
    int o = o0 + s*16 + lr;
    float bias = qb[o];
    int seg = o >> 9, oo = o & 511, h = oo>>6, dd = oo&63;
    size_t hb = (size_t)(b*8+h)*131072;
    #pragma unroll
    for (int a2=0;a2<2;++a2){
      #pragma unroll
      for (int r=0;r<4;++r){
        int n = n0 + a2*16 + lg*4 + r;
        unsigned short val = f2bf(acc[a2][s][r] + bias);
        if (seg==0)
          Qh[hb + (size_t)n*64 + dd] = val;
        else if (seg==1)
          KF[hb + (n>>4)*1024 + (dd>>5)*512 + ((dd>>3)&3)*128 + (n&15)*8 + (dd&7)] = val;
        else
          VF[hb + (n>>5)*2048 + (dd>>4)*512 + ((n>>3)&3)*128 + (dd&15)*8 + (n&7)] = val;
      }
    }
  }
}

// ---------------- K4: flash attention v13 ----------------
// r10 body + (1) block-phase stagger: co-resident blocks rotate their KV
// iteration order so phases desynchronize and braid; (2) s_setprio around
// MFMA clusters (pays once phases diverge). Sums are order-independent.
__global__ __launch_bounds__(256, 4) void k_attn(const unsigned short* __restrict__ Qh,
                                                 const unsigned short* __restrict__ KF,
                                                 const unsigned short* __restrict__ VF,
                                                 const float* __restrict__ rel,
                                                 unsigned short* __restrict__ AOF){
  int did = blockIdx.x;
  int bh = (did & 7)*2 + ((did >> 9) & 1);    // XCD-chunked: 2 heads per XCD
  int qt = (did >> 3) & 63;                   // 64 q-tiles of 32 rows
  int rot = ((did >> 3) & 3) << 1;            // phase stagger among co-resident blocks
  int tid = threadIdx.x, wid = tid>>6, l = tid&63, lr = l&15, lg = l>>4;
  __shared__ float slut[32];
  __shared__ __align__(16) char smem[16384];  // pbuf[4][4096B]; after barrier: combine
  if (tid < 32){
    int bkt = (tid>=1)+(tid>=4)+(tid>=9)+(tid>=16)+(tid>=25);
    slut[tid] = rel[bkt] * 1.44269504f;       // pre-folded log2(e)
  }
  __syncthreads();
  int q0 = qt*32;
  int dq = q0 >> 8, hqA = (q0 >> 4) & 15, hqB = hqA + 1;  // wave-uniform
  int swsq[4];
  #pragma unroll
  for (int r=0;r<4;++r){ int sw = lr - (lg*4+r); swsq[r] = sw*sw; }
  const unsigned short* Qb = Qh + (size_t)bh*131072;
  const unsigned short* Kb = KF + (size_t)bh*131072;
  const unsigned short* Vb = VF + (size_t)bh*131072;
  bfv8 qf0A = *(const bfv8*)(Qb + (size_t)(q0+lr)*64 + lg*8);
  bfv8 qf1A = *(const bfv8*)(Qb + (size_t)(q0+lr)*64 + 32 + lg*8);
  bfv8 qf0B = *(const bfv8*)(Qb + (size_t)(q0+16+lr)*64 + lg*8);
  bfv8 qf1B = *(const bfv8*)(Qb + (size_t)(q0+16+lr)*64 + 32 + lg*8);
  f4v oA[4], oB[4];
  #pragma unroll
  for (int i2=0;i2<4;++i2){ oA[i2] = (f4v){0.f,0.f,0.f,0.f}; oB[i2] = (f4v){0.f,0.f,0.f,0.f}; }
  float lsA = 0.f, lsB = 0.f;
  char* pwA = smem + wid*4096;
  char* pwB = pwA + 2048;
  int swz = (lr&7)<<4;
  #pragma unroll
  for (int it2=0; it2<8; ++it2){
    int it = (it2 + rot) & 7;                 // rotated visit order (sum-commutative)
    int itg = wid*8 + it;                     // global 64-KV tile index
    f4v sa[4], sb[4];
    #pragma unroll
    for (int t=0;t<4;++t){ sa[t] = (f4v){0.f,0.f,0.f,0.f}; sb[t] = (f4v){0.f,0.f,0.f,0.f}; }
    __builtin_amdgcn_s_setprio(1);
    #pragma unroll
    for (int t=0;t<4;++t){
      const unsigned short* kb = Kb + (size_t)(itg*4 + t)*1024 + l*8;
      bfv8 k0 = *(const bfv8*)kb;
      bfv8 k1 = *(const bfv8*)(kb + 512);
      sa[t] = mfma16(k0, qf0A, sa[t]);        // S^T: A=K rows (j), B=Q rows (q)
      sa[t] = mfma16(k1, qf1A, sa[t]);
      sb[t] = mfma16(k0, qf0B, sb[t]);
      sb[t] = mfma16(k1, qf1B, sb[t]);
    }
    __builtin_amdgcn_s_setprio(0);
    int dj = itg>>2; int sd = dq-dj; int sds = sd*sd;
    int hj0 = (itg&3)*4;
    // ---- half A softmax (exp2-folded) ----
    #pragma unroll
    for (int t=0;t<4;++t){
      int sh = hqA - (hj0+t); int sdh = sds + sh*sh;
      float p0 = fexp2(fmaf(sa[t][0], 0.180336878f, slut[(sdh+swsq[0])>>4]));
      float p1 = fexp2(fmaf(sa[t][1], 0.180336878f, slut[(sdh+swsq[1])>>4]));
      float p2 = fexp2(fmaf(sa[t][2], 0.180336878f, slut[(sdh+swsq[2])>>4]));
      float p3 = fexp2(fmaf(sa[t][3], 0.180336878f, slut[(sdh+swsq[3])>>4]));
      lsA += (p0+p1)+(p2+p3);
      uint2 w; w.x = cvtpk(p0,p1); w.y = cvtpk(p2,p3);
      *(uint2*)(pwA + lr*128 + ((32*t + 8*lg) ^ swz)) = w;
    }
    // ---- half B softmax ----
    #pragma unroll
    for (int t=0;t<4;++t){
      int sh = hqB - (hj0+t); int sdh = sds + sh*sh;
      float p0 = fexp2(fmaf(sb[t][0], 0.180336878f, slut[(sdh+swsq[0])>>4]));
      float p1 = fexp2(fmaf(sb[t][1], 0.180336878f, slut[(sdh+swsq[1])>>4]));
      float p2 = fexp2(fmaf(sb[t][2], 0.180336878f, slut[(sdh+swsq[2])>>4]));
      float p3 = fexp2(fmaf(sb[t][3], 0.180336878f, slut[(sdh+swsq[3])>>4]));
      lsB += (p0+p1)+(p2+p3);
      uint2 w; w.x = cvtpk(p0,p1); w.y = cvtpk(p2,p3);
      *(uint2*)(pwB + lr*128 + ((32*t + 8*lg) ^ swz)) = w;
    }
    // ---- PV: V loads shared by both halves ----
    #pragma unroll
    for (int kt=0;kt<2;++kt){
      bfv8 pfA = *(const bfv8*)(pwA + lr*128 + ((64*kt + 16*lg) ^ swz));
      bfv8 pfB = *(const bfv8*)(pwB + lr*128 + ((64*kt + 16*lg) ^ swz));
      const unsigned short* vb = Vb + (size_t)(itg*2 + kt)*2048 + l*8;
      __builtin_amdgcn_s_setprio(1);
      #pragma unroll
      for (int d2=0;d2<4;++d2){
        bfv8 vf = *(const bfv8*)(vb + d2*512);
        oA[d2] = mfma16(pfA, vf, oA[d2]);
        oB[d2] = mfma16(pfB, vf, oB[d2]);
      }
      __builtin_amdgcn_s_setprio(0);
    }
  }
  lsA += __shfl_xor(lsA, 16); lsA += __shfl_xor(lsA, 32);
  lsB += __shfl_xor(lsB, 16); lsB += __shfl_xor(lsB, 32);
  __syncthreads();                 // all waves done with pbuf; reuse as combine buffers
  float* sOf = (float*)smem;                   // [32][68]
  float* sls = (float*)(smem + 32*68*4);       // [32]
  #pragma unroll 1
  for (int p=0; p<4; ++p){
    if (wid == p){
      if (p == 0){
        #pragma unroll
        for (int r=0;r<4;++r){
          #pragma unroll
          for (int d2=0;d2<4;++d2){
            sOf[(lg*4+r)*68 + d2*16+lr] = oA[d2][r];
            sOf[(16+lg*4+r)*68 + d2*16+lr] = oB[d2][r];
          }
        }
        if (l < 16){ sls[l] = lsA; sls[16+l] = lsB; }
      } else {
        #pragma unroll
        for (int r=0;r<4;++r){
          #pragma unroll
          for (int d2=0;d2<4;++d2){
            sOf[(lg*4+r)*68 + d2*16+lr] += oA[d2][r];
            sOf[(16+lg*4+r)*68 + d2*16+lr] += oB[d2][r];
          }
        }
        if (l < 16){ sls[l] += lsA; sls[16+l] += lsB; }
      }
    }
    __syncthreads();
  }
  int b = bh>>3, h = bh&7;
  int col = tid & 63, rw = tid >> 6;
  #pragma unroll
  for (int k=0;k<8;++k){
    int row = rw*8 + k;
    float v = sOf[row*68 + col] / sls[row];
    int n = q0 + row;
    size_t off = (size_t)(b*128 + (n>>4))*8192 + (size_t)(h*2 + (col>>5))*512
               + ((col>>3)&3)*128 + (n&15)*8 + (col&7);
    AOF[off] = f2bf(v);
  }
}

// ---------------- K5: proj GEMM + bias + residual (fragment-ordered operands) ----------------
__global__ __launch_bounds__(256) void k_proj(const unsigned short* __restrict__ AOF,
                                              const unsigned short* __restrict__ WPF,
                                              const float* __restrict__ pb,
                                              const float* __restrict__ x,
                                              float* __restrict__ out){
  int nt = blockIdx.x & 31, ot = (blockIdx.x>>5)&7, b = blockIdx.x>>8;
  int tid = threadIdx.x, wid = tid>>6, l = tid&63, lr = l&15, lg = l>>4;
  int o0 = ot*64 + wid*16, n0 = nt*64;
  f4v acc[4];
  #pragma unroll
  for (int t=0;t<4;++t) acc[t] = (f4v){0.f,0.f,0.f,0.f};
  const unsigned short* arow = WPF + (size_t)(o0>>4)*8192 + l*8;
  const unsigned short* brow = AOF + (size_t)(b*128 + (n0>>4))*8192 + l*8;
  #pragma unroll
  for (int kc=0;kc<16;++kc){
    bfv8 a = *(const bfv8*)(arow + kc*512);
    #pragma unroll
    for (int t=0;t<4;++t){
      bfv8 bb = *(const bfv8*)(brow + t*8192 + kc*512);
      acc[t] = mfma16(a, bb, acc[t]);
    }
  }
  #pragma unroll
  for (int r=0;r<4;++r){
    int o = o0 + lg*4 + r;
    float bias = pb[o];
    #pragma unroll
    for (int t=0;t<4;++t){
      int n = n0 + t*16 + lr;
      size_t idx = ((size_t)(b*512)+o)*2048 + n;
      out[idx] = acc[t][r] + bias + x[idx];
    }
  }
}

extern "C" void kernel_launch(void* const* d_in, const int* in_sizes, int n_in,
                              void* d_out, int out_size, void* d_ws, size_t ws_size,
                              hipStream_t stream){
  const float* x     = (const float*)d_in[0];
  const float* gnw   = (const float*)d_in[1];
  const float* gnb   = (const float*)d_in[2];
  const float* qkvw  = (const float*)d_in[3];
  const float* qkvb  = (const float*)d_in[4];
  const float* projw = (const float*)d_in[5];
  const float* projb = (const float*)d_in[6];
  const float* rel   = (const float*)d_in[7];
  float* out = (float*)d_out;
  char* ws = (char*)d_ws;
  float2* part           = (float2*)ws;                       // 2 KB
  unsigned short* WQF    = (unsigned short*)(ws + 4096);      // 1536x512 bf16, frag order
  unsigned short* WPF    = (unsigned short*)(ws + 1576960);   // 512x512 bf16, frag order
  unsigned short* AF     = (unsigned short*)(ws + 2101248);   // [2][2048][512] frag order
  unsigned short* Qh     = (unsigned short*)(ws + 6295552);   // [2][8][2048][64] row-major
  unsigned short* KF     = (unsigned short*)(ws + 10489856);  // [2][8] K frag order
  unsigned short* VF     = (unsigned short*)(ws + 14684160);  // [2][8] V frag order
  unsigned short* AOF    = (unsigned short*)(ws + 18878464);  // [2][2048][512] frag order

  hipLaunchKernelGGL(k_prep,   dim3(1280), dim3(256), 0, stream, qkvw, projw, x, WQF, WPF, part);
  hipLaunchKernelGGL(k_gnnorm, dim3(512),  dim3(256), 0, stream, x, part, gnw, gnb, AF);
  hipLaunchKernelGGL(k_qkv,    dim3(768),  dim3(256), 0, stream, AF, WQF, qkvb, Qh, KF, VF);
  hipLaunchKernelGGL(k_attn,   dim3(1024), dim3(256), 0, stream, Qh, KF, VF, rel, AOF);
  hipLaunchKernelGGL(k_proj,   dim3(512),  dim3(256), 0, stream, AOF, WPF, projb, x, out);
}